// Round 12
// baseline (3844.721 us; speedup 1.0000x reference)
//
#include <hip/hip_runtime.h>
#include <stdint.h>

// NpiLstm: T=512, B=128, H=1024, IN=64 (63 x-features + 1 feedback)
// Feedback folded into recurrent weights: W_hh' = W_hh + w_fb (x) W_lin.
// R12: TAGGED IN-BAND h exchange — each h element published as one u32
// word (step-tag<<16 | int8-hi<<8 | int8-lo). Consumers poll the exact
// words they consume until tags match: poll success == data in registers.
// Removes flag stores, producer drains, and the post-poll h-load (~2 IC
// round-trips/step off the serial chain that R5-R11 never touched).
// WAR-safe by induction: overwrite at t+2 requires tags t+1 from all 32
// producers; a producer's t+1 tags follow its t+1 barrier which follows
// its own step-t reads. Geometry = R5 (proven fastest): 256 blocks 1/CU,
// 8 groups x 32; group g = batch rows [16g,16g+16); block mb owns h-cols
// [32mb,32mb+32) = 128 gate-cols. int8 weights (R10-proven numerics)
// streamed to registers R5-style (loads overlap the poll); K = 17 x 64.
// Wave wv: x-ntiles {2wv,2wv+1} + h-taus [4wv,4wv+4) -> 68 MFMA/wave.

typedef int int4v __attribute__((ext_vector_type(4)));
typedef float float4v __attribute__((ext_vector_type(4)));

#define C_HI  (1.0f/127.0f)
#define C_HLO (1.0f/32258.0f)   // h ~ qhi/127 + qlo/32258
#define C_XLO (1.0f/16129.0f)   // x ~ sx*(qhi/127 + qlo/16129)

__device__ __forceinline__ float sigm(float x) { return 1.0f / (1.0f + __expf(-x)); }
__device__ __forceinline__ float tanh_f(float x) {
  float ax = fabsf(x);
  float e = __expf(-2.0f * ax);
  float r = (1.0f - e) / (1.0f + e);
  return x < 0.0f ? -r : r;
}
#define MFMA_I8(A, B, C) __builtin_amdgcn_mfma_i32_16x16x64_i8((A), (B), (C), 0, 0, 0)

// ---- zero tagged-h planes (tag0|0 == valid zeros for t=1) + sx ----
__global__ void initz(unsigned int* __restrict__ Htag, unsigned int* __restrict__ sxu) {
  int idx = blockIdx.x * 256 + threadIdx.x;   // 1024 blocks -> 0..262143
  Htag[idx] = 0u;                              // 2 parities x 128 x 1024 words
  if (idx == 0) *sxu = 0u;
}

// ---- global amax of x -> sx ----
__global__ void prep_ax(const float* __restrict__ x, unsigned int* __restrict__ sxu) {
  int tid = blockIdx.x * 256 + threadIdx.x;   // 1024 blocks
  float am = 0.f;
  for (int i = tid; i < 4128768; i += 262144) am = fmaxf(am, fabsf(x[i]));
  for (int d = 1; d < 64; d <<= 1) am = fmaxf(am, __shfl_xor(am, d));
  __shared__ float sam[4];
  if ((threadIdx.x & 63) == 0) sam[threadIdx.x >> 6] = am;
  __syncthreads();
  if (threadIdx.x == 0) {
    float m = fmaxf(fmaxf(sam[0], sam[1]), fmaxf(sam[2], sam[3]));
    atomicMax(sxu, __float_as_uint(m));   // floats >= 0: bit order = value order
  }
}

// ---- fold weights, per-column amax, quantize to int8; biases ----
// Wq row j: k [0,64) = x (63 feats + 1 zero); [64,1088) = folded W_hh.
__global__ void prep_wq(const float* __restrict__ W_ih, const float* __restrict__ W_hh,
                        const float* __restrict__ W_lin, const float* __restrict__ b_ih,
                        const float* __restrict__ b_hh, const float* __restrict__ b_lin,
                        signed char* __restrict__ Wq, float* __restrict__ scol,
                        float* __restrict__ b1, float* __restrict__ b2) {
  int j = blockIdx.x;          // 0..4095
  int tid = threadIdx.x;
  float wfb = W_ih[j * 64 + 63];
  float wv[5];
  float am = 0.f;
#pragma unroll
  for (int it = 0; it < 5; ++it) {
    int k = tid + 256 * it;
    float w = 0.f;
    if (k < 63) w = W_ih[j * 64 + k];
    else if (k >= 64 && k < 1088) {
      int kk = k - 64;
      w = W_hh[j * 1024 + kk] + wfb * W_lin[kk];
    }
    wv[it] = w;
    am = fmaxf(am, fabsf(w));
  }
  for (int d = 1; d < 64; d <<= 1) am = fmaxf(am, __shfl_xor(am, d));
  __shared__ float sam[4];
  if ((tid & 63) == 0) sam[tid >> 6] = am;
  __syncthreads();
  float amax = fmaxf(fmaxf(sam[0], sam[1]), fmaxf(sam[2], sam[3]));
  float sc = fmaxf(amax, 1e-30f);
  float qs = 127.0f / sc;
#pragma unroll
  for (int it = 0; it < 5; ++it) {
    int k = tid + 256 * it;
    if (k < 1088) Wq[(size_t)j * 1088 + k] = (signed char)(int)rintf(wv[it] * qs);
  }
  if (tid == 0) {
    scol[j] = sc * (1.0f / 127.0f);
    float base = b_ih[j] + b_hh[j];
    b1[j] = base + 1e-9f * wfb;      // step 1: feedback value is INIT_OUT
    b2[j] = base + b_lin[0] * wfb;   // steps >=2: folded b_lin feedback
  }
}

// ---- x -> two-channel int8, padded to 64 channels ----
__global__ void prep_x2(const float* __restrict__ x, const unsigned int* __restrict__ sxu,
                        signed char* __restrict__ xh, signed char* __restrict__ xl) {
  int idx = blockIdx.x * 256 + threadIdx.x;   // < 4194304 exactly
  int c = idx & 63;
  int bi = idx >> 6;
  float sx = fmaxf(__uint_as_float(*sxu), 1e-30f);
  float v = (c < 63) ? x[bi * 63 + c] : 0.f;
  float vn = (v / sx) * 127.0f;        // [-127, 127]
  float qh = rintf(vn);
  float ql = rintf((vn - qh) * 127.0f);
  xh[idx] = (signed char)(int)qh;
  xl[idx] = (signed char)(int)ql;
}

// ---- persistent recurrent kernel: 256 blocks (1/CU), 256 threads ----
__global__ __launch_bounds__(256, 1) void lstm_rec(
    const signed char* __restrict__ Wq, const float* __restrict__ scol,
    const signed char* __restrict__ xqh, const signed char* __restrict__ xql,
    const unsigned int* __restrict__ sxu, const float* __restrict__ b1,
    const float* __restrict__ b2, const float* __restrict__ Wlin,
    char* __restrict__ Htag, float* __restrict__ outp) {
  const int tid = threadIdx.x;
  const int bid = blockIdx.x;
  const int g = bid & 7;          // group: batch rows [16g,16g+16)
  const int mb = bid >> 3;        // [0,32): h-cols [32mb,32mb+32)
  const int wv = tid >> 6;
  const int ln = tid & 63;
  const int lr = ln & 15;         // MFMA fragment row/col within 16
  const int lq = ln >> 4;         // k-quarter
  const int rp = wv * 2 + (ln >> 5);  // pointwise row-pair index 0..7
  const int c = ln & 31;              // pointwise col 0..31

  __shared__ __align__(16) float pbuf[2][4][8][16][20];  // [par][wave][nt][col][row+pad]

  // ---- weight B-frags (int8): this wave's 4 h-taus x 8 nt + 2 x-nt ----
  int4v bqh[4][8], bqx[2];
#pragma unroll
  for (int nt = 0; nt < 8; ++nt) {
    const signed char* wrow =
        Wq + (size_t)((nt >> 1) * 1024 + mb * 32 + (nt & 1) * 16 + lr) * 1088;
#pragma unroll
    for (int j = 0; j < 4; ++j)
      bqh[j][nt] = *reinterpret_cast<const int4v*>(wrow + 64 + (wv * 4 + j) * 64 + lq * 16);
  }
#pragma unroll
  for (int m = 0; m < 2; ++m) {
    int nt = wv * 2 + m;
    bqx[m] = *reinterpret_cast<const int4v*>(
        Wq + (size_t)((nt >> 1) * 1024 + mb * 32 + (nt & 1) * 16 + lr) * 1088 + lq * 16);
  }

  // per-lane column scales for all 8 ntiles (C/D col = lr)
  float scq[8];
#pragma unroll
  for (int nt = 0; nt < 8; ++nt)
    scq[nt] = scol[(nt >> 1) * 1024 + mb * 32 + (nt & 1) * 16 + lr];
  const float sx = fmaxf(__uint_as_float(*sxu), 1e-30f);

  // tagged-load base byte offset (parity-independent part)
  const int vbase0 = (g * 16 + lr) * 4096 + wv * 1024 + lq * 64;

  const int gcb = mb * 32 + c;    // pointwise gate/h column
  const int nlo = c >> 4;
  const int cc = c & 15;
  float bias2[4];
#pragma unroll
  for (int q = 0; q < 4; ++q) bias2[q] = b2[q * 1024 + gcb];
  const float wl = Wlin[gcb];
  float cs0 = 0.f, cs1 = 0.f;     // cell states (rows 2rp, 2rp+1)

  for (int t = 1; t < 512; ++t) {
    const int par = (t - 1) & 1;
    const unsigned int etag = (unsigned int)(t - 1) << 16;
    // --- x A-frags (plain cached loads; per-wave x-ntile split) ---
    size_t xoff = (size_t)t * 8192 + (g * 16 + lr) * 64 + lq * 16;
    int4v axh = *reinterpret_cast<const int4v*>(xqh + xoff);
    int4v axl = *reinterpret_cast<const int4v*>(xql + xoff);

    // --- poll the tagged h words this wave consumes (data == flag) ---
    int voffj[4];
#pragma unroll
    for (int j = 0; j < 4; ++j) voffj[j] = vbase0 + par * 524288 + j * 256;
    int4v hw[4][4];
    int guard = 0;
    for (;;) {
#pragma unroll
      for (int j = 0; j < 4; ++j) {
        asm volatile("global_load_dwordx4 %0, %1, %2 sc0 sc1"
                     : "=v"(hw[j][0]) : "v"(voffj[j]), "s"(Htag));
        asm volatile("global_load_dwordx4 %0, %1, %2 offset:16 sc0 sc1"
                     : "=v"(hw[j][1]) : "v"(voffj[j]), "s"(Htag));
        asm volatile("global_load_dwordx4 %0, %1, %2 offset:32 sc0 sc1"
                     : "=v"(hw[j][2]) : "v"(voffj[j]), "s"(Htag));
        asm volatile("global_load_dwordx4 %0, %1, %2 offset:48 sc0 sc1"
                     : "=v"(hw[j][3]) : "v"(voffj[j]), "s"(Htag));
      }
      asm volatile("s_waitcnt vmcnt(0)" ::: "memory");
      unsigned int accu = 0u;
#pragma unroll
      for (int j = 0; j < 4; ++j)
#pragma unroll
        for (int i = 0; i < 4; ++i) {
          accu |= ((unsigned int)hw[j][i].x ^ etag);
          accu |= ((unsigned int)hw[j][i].y ^ etag);
          accu |= ((unsigned int)hw[j][i].z ^ etag);
          accu |= ((unsigned int)hw[j][i].w ^ etag);
        }
      if (__all((accu & 0xffff0000u) == 0u)) break;
      if (++guard > (1 << 17)) break;   // hang-safety valve
    }
    __builtin_amdgcn_sched_barrier(0);

    // --- MFMA: extract per tau, accumulate i32; B-frags reused across ch ---
    int4v hh[8], hl[8];
#pragma unroll
    for (int nt = 0; nt < 8; ++nt) {
      hh[nt] = (int4v){0, 0, 0, 0};
      hl[nt] = (int4v){0, 0, 0, 0};
    }
#pragma unroll
    for (int j = 0; j < 4; ++j) {
      int4v ah, al;
#pragma unroll
      for (int d = 0; d < 4; ++d) {
        unsigned int w0 = (unsigned int)hw[j][d].x, w1 = (unsigned int)hw[j][d].y;
        unsigned int w2 = (unsigned int)hw[j][d].z, w3 = (unsigned int)hw[j][d].w;
        unsigned int t01h = __builtin_amdgcn_perm(w1, w0, 0x00000501u);
        unsigned int t23h = __builtin_amdgcn_perm(w3, w2, 0x00000501u);
        ah[d] = (int)__builtin_amdgcn_perm(t23h, t01h, 0x05040100u);
        unsigned int t01l = __builtin_amdgcn_perm(w1, w0, 0x00000400u);
        unsigned int t23l = __builtin_amdgcn_perm(w3, w2, 0x00000400u);
        al[d] = (int)__builtin_amdgcn_perm(t23l, t01l, 0x05040100u);
      }
#pragma unroll
      for (int nt = 0; nt < 8; ++nt) {
        hh[nt] = MFMA_I8(ah, bqh[j][nt], hh[nt]);
        hl[nt] = MFMA_I8(al, bqh[j][nt], hl[nt]);
      }
    }
    int4v xh0 = (int4v){0, 0, 0, 0}, xl0 = (int4v){0, 0, 0, 0};
    int4v xh1 = (int4v){0, 0, 0, 0}, xl1 = (int4v){0, 0, 0, 0};
    xh0 = MFMA_I8(axh, bqx[0], xh0);
    xl0 = MFMA_I8(axl, bqx[0], xl0);
    xh1 = MFMA_I8(axh, bqx[1], xh1);
    xl1 = MFMA_I8(axl, bqx[1], xl1);

    // --- combine to f32 with scales; x folds into this wave's 2 ntiles ---
#pragma unroll
    for (int nt = 0; nt < 8; ++nt) {
      float4v o;
#pragma unroll
      for (int i = 0; i < 4; ++i) {
        float f = (float)hh[nt][i] * C_HI + (float)hl[nt][i] * C_HLO;
        if (nt == wv * 2)
          f += sx * ((float)xh0[i] * C_HI + (float)xl0[i] * C_XLO);
        if (nt == wv * 2 + 1)
          f += sx * ((float)xh1[i] * C_HI + (float)xl1[i] * C_XLO);
        o[i] = scq[nt] * f;
      }
      *reinterpret_cast<float4v*>(&pbuf[par][wv][nt][lr][lq * 4]) = o;
    }
    __syncthreads();   // the ONLY barrier per step (pbuf parity-dbuf'd)

    // --- pointwise: reduce 4 wave-partials, gates -> c,h (2 rows/thread) ---
    float ga0[4], ga1[4];
#pragma unroll
    for (int q = 0; q < 4; ++q) {
      ga0[q] = pbuf[par][0][q * 2 + nlo][cc][2 * rp] + pbuf[par][1][q * 2 + nlo][cc][2 * rp] +
               pbuf[par][2][q * 2 + nlo][cc][2 * rp] + pbuf[par][3][q * 2 + nlo][cc][2 * rp];
      ga1[q] = pbuf[par][0][q * 2 + nlo][cc][2 * rp + 1] + pbuf[par][1][q * 2 + nlo][cc][2 * rp + 1] +
               pbuf[par][2][q * 2 + nlo][cc][2 * rp + 1] + pbuf[par][3][q * 2 + nlo][cc][2 * rp + 1];
    }
    float lb0 = bias2[0], lb1 = bias2[1], lb2 = bias2[2], lb3 = bias2[3];
    if (t == 1) {
      lb0 = b1[gcb];
      lb1 = b1[1024 + gcb];
      lb2 = b1[2048 + gcb];
      lb3 = b1[3072 + gcb];
    }
    float i0 = sigm(ga0[0] + lb0), f0 = sigm(ga0[1] + lb1);
    float G0 = tanh_f(ga0[2] + lb2), o0 = sigm(ga0[3] + lb3);
    float i1 = sigm(ga1[0] + lb0), f1 = sigm(ga1[1] + lb1);
    float G1 = tanh_f(ga1[2] + lb2), o1 = sigm(ga1[3] + lb3);
    cs0 = f0 * cs0 + i0 * G0;
    cs1 = f1 * cs1 + i1 * G1;
    float hv0 = o0 * tanh_f(cs0);
    float hv1 = o1 * tanh_f(cs1);

    // --- publish tagged h words (tag t); no drain, no flag ---
    const unsigned int stag = (unsigned int)t << 16;
    float s0 = hv0 * 127.0f, q0f = rintf(s0), r0f = rintf((s0 - q0f) * 254.0f);
    float s1 = hv1 * 127.0f, q1f = rintf(s1), r1f = rintf((s1 - q1f) * 254.0f);
    unsigned int wrd0 = stag | ((((int)q0f) & 0xff) << 8) | (((int)r0f) & 0xff);
    unsigned int wrd1 = stag | ((((int)q1f) & 0xff) << 8) | (((int)r1f) & 0xff);
    const int r0 = g * 16 + rp * 2;
    char* st0 = Htag + (t & 1) * 524288 + r0 * 4096 + gcb * 4;
    asm volatile("global_store_dword %0, %1, off sc0 sc1" :: "v"(st0), "v"(wrd0) : "memory");
    asm volatile("global_store_dword %0, %1, off sc0 sc1" :: "v"(st0 + 4096), "v"(wrd1) : "memory");

    // --- W_lin partial for this block's 32 cols (off-chain) ---
    float pa = hv0 * wl, pb = hv1 * wl;
    pa += __shfl_xor(pa, 1); pb += __shfl_xor(pb, 1);
    pa += __shfl_xor(pa, 2); pb += __shfl_xor(pb, 2);
    pa += __shfl_xor(pa, 4); pb += __shfl_xor(pb, 4);
    pa += __shfl_xor(pa, 8); pb += __shfl_xor(pb, 8);
    pa += __shfl_xor(pa, 16); pb += __shfl_xor(pb, 16);
    if (c == 0) {
      outp[(size_t)(t * 128 + r0) * 32 + mb] = pa;
      outp[(size_t)(t * 128 + r0 + 1) * 32 + mb] = pb;
    }
  }
}

// ---- out[t][b] = b_lin + sum_mb outp[t][b][mb]; rows t=0 -> INIT_OUT ----
__global__ void finalize(const float* __restrict__ outp, const float* __restrict__ b_lin,
                         float* __restrict__ out) {
  int tid = threadIdx.x;
  int ln = tid & 63;
  int wv = tid >> 6;
  int half = ln >> 5;
  int lane = ln & 31;
  int row = blockIdx.x * 8 + wv * 2 + half;   // < 65536
  float v = outp[(size_t)row * 32 + lane];
  v += __shfl_xor(v, 1);
  v += __shfl_xor(v, 2);
  v += __shfl_xor(v, 4);
  v += __shfl_xor(v, 8);
  v += __shfl_xor(v, 16);
  if (lane == 0) out[row] = (row < 128) ? 1e-9f : (v + b_lin[0]);
}

extern "C" void kernel_launch(void* const* d_in, const int* in_sizes, int n_in,
                              void* d_out, int out_size, void* d_ws, size_t ws_size,
                              hipStream_t stream) {
  const float* x = (const float*)d_in[0];
  const float* W_ih = (const float*)d_in[1];
  const float* W_hh = (const float*)d_in[2];
  const float* b_ih = (const float*)d_in[3];
  const float* b_hh = (const float*)d_in[4];
  const float* W_lin = (const float*)d_in[5];
  const float* b_lin = (const float*)d_in[6];
  float* out = (float*)d_out;

  char* ws = (char*)d_ws;
  const size_t O_WQ   = 0;           // 4096*1088      = 4456448
  const size_t O_SCOL = 4456448;     // 16384
  const size_t O_B1   = 4472832;     // 16384
  const size_t O_B2   = 4489216;     // 16384
  const size_t O_SX   = 4505600;     // 64
  const size_t O_XH   = 4505664;     // 512*128*64     = 4194304
  const size_t O_XL   = 8699968;     // 4194304
  const size_t O_HT   = 12894272;    // 2*128*1024*4   = 1048576
  const size_t O_OUTP = 13942848;    // 512*128*32*4   = 8388608
  const size_t O_END  = 22331456;
  if (ws_size < O_END) return;       // insufficient scratch -> fail loudly

  signed char* Wq = (signed char*)(ws + O_WQ);
  float* scol = (float*)(ws + O_SCOL);
  float* b1 = (float*)(ws + O_B1);
  float* b2 = (float*)(ws + O_B2);
  unsigned int* sxu = (unsigned int*)(ws + O_SX);
  signed char* xqh = (signed char*)(ws + O_XH);
  signed char* xql = (signed char*)(ws + O_XL);
  char* Htag = ws + O_HT;
  float* outp = (float*)(ws + O_OUTP);

  initz<<<1024, 256, 0, stream>>>((unsigned int*)Htag, sxu);
  prep_ax<<<1024, 256, 0, stream>>>(x, sxu);
  prep_wq<<<4096, 256, 0, stream>>>(W_ih, W_hh, W_lin, b_ih, b_hh, b_lin, Wq, scol, b1, b2);
  prep_x2<<<16384, 256, 0, stream>>>(x, sxu, xqh, xql);
  lstm_rec<<<256, 256, 0, stream>>>(Wq, scol, xqh, xql, sxu, b1, b2, W_lin, Htag, outp);
  finalize<<<8192, 256, 0, stream>>>(outp, b_lin, out);
}

// Round 13
// 3032.968 us; speedup vs baseline: 1.2676x; 1.2676x over previous
//
#include <hip/hip_runtime.h>
#include <stdint.h>

// NpiLstm: T=512, B=128, H=1024, IN=64 (63 x-features + 1 feedback)
// Feedback folded into recurrent weights: W_hh' = W_hh + w_fb (x) W_lin.
// R13 = R5's proven skeleton (256 blocks 1/CU, 8 groups x 32, M=16 rows,
// 32 h-cols/block, flag poll + 2 barriers, sc0sc1 exchange) with BOTH
// dominant costs removed at once:
//  - weights int8 LDS-resident (14/16 h K-tiles in 112KB LDS; wave3's 2
//    tiles + x-frags pinned in regs) -> no 294KB/step L2 weight stream.
//  - h as ONE packed short per element (int8 hi<<8 | int8 lo residual,
//    R10/R11-proven numerics) -> IC exchange bytes identical to R5
//    (8 dwordx4/wave loads, 2 short stores), channels split via v_perm.
// i8 MFMA 16x16x64; K = 17x64 (tau0 = x, 16 h-taus); 4-way K-split;
// wave wv polls only its 8 producer blocks (32 flags).

typedef int int4v __attribute__((ext_vector_type(4)));
typedef float float4v __attribute__((ext_vector_type(4)));

#define C_HI  (1.0f/127.0f)
#define C_HLO (1.0f/32258.0f)   // h ~ qhi/127 + qlo/32258
#define C_XLO (1.0f/16129.0f)   // x ~ sx*(qhi/127 + qlo/16129)

__device__ __forceinline__ float sigm(float x) { return 1.0f / (1.0f + __expf(-x)); }
__device__ __forceinline__ float tanh_f(float x) {
  float ax = fabsf(x);
  float e = __expf(-2.0f * ax);
  float r = (1.0f - e) / (1.0f + e);
  return x < 0.0f ? -r : r;
}
#define MFMA_I8(A, B, C) __builtin_amdgcn_mfma_i32_16x16x64_i8((A), (B), (C), 0, 0, 0)

// ---- zero packed-h planes + flags + sx ----
__global__ void initz(unsigned int* __restrict__ Hp, int* __restrict__ flags,
                      unsigned int* __restrict__ sxu) {
  int idx = blockIdx.x * 256 + threadIdx.x;   // 512 blocks -> 0..131071
  Hp[idx] = 0u;                                // 2 par x 128 rows x 1024 shorts
  if (idx < 1024) flags[idx] = 0;
  if (idx == 0) *sxu = 0u;
}

// ---- global amax of x -> sx ----
__global__ void prep_ax(const float* __restrict__ x, unsigned int* __restrict__ sxu) {
  int tid = blockIdx.x * 256 + threadIdx.x;   // 1024 blocks
  float am = 0.f;
  for (int i = tid; i < 4128768; i += 262144) am = fmaxf(am, fabsf(x[i]));
  for (int d = 1; d < 64; d <<= 1) am = fmaxf(am, __shfl_xor(am, d));
  __shared__ float sam[4];
  if ((threadIdx.x & 63) == 0) sam[threadIdx.x >> 6] = am;
  __syncthreads();
  if (threadIdx.x == 0) {
    float m = fmaxf(fmaxf(sam[0], sam[1]), fmaxf(sam[2], sam[3]));
    atomicMax(sxu, __float_as_uint(m));   // floats >= 0: bit order = value order
  }
}

// ---- fold weights, per-column amax, quantize to int8; biases ----
__global__ void prep_wq(const float* __restrict__ W_ih, const float* __restrict__ W_hh,
                        const float* __restrict__ W_lin, const float* __restrict__ b_ih,
                        const float* __restrict__ b_hh, const float* __restrict__ b_lin,
                        signed char* __restrict__ Wq, float* __restrict__ scol,
                        float* __restrict__ b1, float* __restrict__ b2) {
  int j = blockIdx.x;          // 0..4095
  int tid = threadIdx.x;
  float wfb = W_ih[j * 64 + 63];
  float wv[5];
  float am = 0.f;
#pragma unroll
  for (int it = 0; it < 5; ++it) {
    int k = tid + 256 * it;
    float w = 0.f;
    if (k < 63) w = W_ih[j * 64 + k];
    else if (k >= 64 && k < 1088) {
      int kk = k - 64;
      w = W_hh[j * 1024 + kk] + wfb * W_lin[kk];
    }
    wv[it] = w;
    am = fmaxf(am, fabsf(w));
  }
  for (int d = 1; d < 64; d <<= 1) am = fmaxf(am, __shfl_xor(am, d));
  __shared__ float sam[4];
  if ((tid & 63) == 0) sam[tid >> 6] = am;
  __syncthreads();
  float amax = fmaxf(fmaxf(sam[0], sam[1]), fmaxf(sam[2], sam[3]));
  float sc = fmaxf(amax, 1e-30f);
  float qs = 127.0f / sc;
#pragma unroll
  for (int it = 0; it < 5; ++it) {
    int k = tid + 256 * it;
    if (k < 1088) Wq[(size_t)j * 1088 + k] = (signed char)(int)rintf(wv[it] * qs);
  }
  if (tid == 0) {
    scol[j] = sc * (1.0f / 127.0f);
    float base = b_ih[j] + b_hh[j];
    b1[j] = base + 1e-9f * wfb;      // step 1: feedback value is INIT_OUT
    b2[j] = base + b_lin[0] * wfb;   // steps >=2: folded b_lin feedback
  }
}

// ---- x -> two-channel int8 planes, padded to 64 channels ----
__global__ void prep_x2(const float* __restrict__ x, const unsigned int* __restrict__ sxu,
                        signed char* __restrict__ xh, signed char* __restrict__ xl) {
  int idx = blockIdx.x * 256 + threadIdx.x;   // < 4194304 exactly
  int c = idx & 63;
  int bi = idx >> 6;
  float sx = fmaxf(__uint_as_float(*sxu), 1e-30f);
  float v = (c < 63) ? x[bi * 63 + c] : 0.f;
  float vn = (v / sx) * 127.0f;        // [-127, 127]
  float qh = rintf(vn);
  float ql = rintf((vn - qh) * 127.0f);
  xh[idx] = (signed char)(int)qh;
  xl[idx] = (signed char)(int)ql;
}

// ---- persistent recurrent kernel: 256 blocks (1/CU), 256 threads ----
// wave wv: h-taus [4wv,4wv+4) (h-cols [256wv,256wv+256)) + its 2 x-ntiles.
// Producers for wave wv: blocks mb in [8wv,8wv+8) -> 32 flags.
__global__ __launch_bounds__(256, 1) void lstm_rec(
    const signed char* __restrict__ Wq, const float* __restrict__ scol,
    const signed char* __restrict__ xqh, const signed char* __restrict__ xql,
    const unsigned int* __restrict__ sxu, const float* __restrict__ b1,
    const float* __restrict__ b2, const float* __restrict__ Wlin,
    char* __restrict__ Hp, float* __restrict__ outp, int* __restrict__ flags) {
  const int tid = threadIdx.x;
  const int bid = blockIdx.x;
  const int g = bid & 7;          // group: batch rows [16g,16g+16)
  const int mb = bid >> 3;        // [0,32): h-cols [32mb,32mb+32)
  const int wv = tid >> 6;
  const int ln = tid & 63;
  const int lr = ln & 15;         // MFMA fragment row/col within 16
  const int lq = ln >> 4;         // k-quarter
  const int rp = wv * 2 + (ln >> 5);  // pointwise row-pair index 0..7
  const int c = ln & 31;              // pointwise col 0..31

  __shared__ __align__(16) char wlds[114688];            // h-taus 0..13 x 8nt x 1KB
  __shared__ __align__(16) float pbuf[4][8][16][20];     // [wave][nt][col][row+pad]

  // ---- stage int8 weights (h-taus 0..13) to LDS, once ----
  for (int s = tid; s < 7168; s += 256) {   // 8nt x 14tau x 64 lanes
    int nt = s / 896;
    int rem = s - nt * 896;
    int tau = rem >> 6;
    int l = rem & 63;
    int row = (nt >> 1) * 1024 + mb * 32 + (nt & 1) * 16 + (l & 15);
    int4v v = *reinterpret_cast<const int4v*>(
        Wq + (size_t)row * 1088 + 64 + tau * 64 + (l >> 4) * 16);
    *reinterpret_cast<int4v*>(wlds + (nt * 14 + tau) * 1024 + l * 16) = v;
  }
  __syncthreads();

  // ---- register-pinned B-frags: per-wave x (2 nt); wave3: h-taus 14,15 ----
  int4v bqx[2];
#pragma unroll
  for (int m = 0; m < 2; ++m) {
    int nt = wv * 2 + m;
    int row = (nt >> 1) * 1024 + mb * 32 + (nt & 1) * 16 + lr;
    bqx[m] = *reinterpret_cast<const int4v*>(Wq + (size_t)row * 1088 + lq * 16);
    asm volatile("" : "+v"(bqx[m]));
  }
  int4v bs[2][8];
  if (wv == 3) {
#pragma unroll
    for (int t2 = 0; t2 < 2; ++t2)
#pragma unroll
      for (int nt = 0; nt < 8; ++nt) {
        int row = (nt >> 1) * 1024 + mb * 32 + (nt & 1) * 16 + lr;
        bs[t2][nt] = *reinterpret_cast<const int4v*>(
            Wq + (size_t)row * 1088 + 64 + (14 + t2) * 64 + lq * 16);
      }
  }
#pragma unroll
  for (int t2 = 0; t2 < 2; ++t2)
#pragma unroll
    for (int nt = 0; nt < 8; ++nt) asm volatile("" : "+v"(bs[t2][nt]));

  // per-lane column scales for all 8 ntiles (C/D col = lr)
  float scq[8];
#pragma unroll
  for (int nt = 0; nt < 8; ++nt)
    scq[nt] = scol[(nt >> 1) * 1024 + mb * 32 + (nt & 1) * 16 + lr];
  const float sx = fmaxf(__uint_as_float(*sxu), 1e-30f);

  // h A-frag byte offsets (within one parity plane of packed shorts)
  int hoffA[4];
#pragma unroll
  for (int j = 0; j < 4; ++j)
    hoffA[j] = (g * 16 + lr) * 2048 + (wv * 4 + j) * 128 + lq * 32;

  const int gcb = mb * 32 + c;    // pointwise gate/h column
  const int nlo = c >> 4;
  const int cc = c & 15;
  float bias2[4];
#pragma unroll
  for (int q = 0; q < 4; ++q) bias2[q] = b2[q * 1024 + gcb];
  const float wl = Wlin[gcb];
  float cs0 = 0.f, cs1 = 0.f;     // cell states (rows 2rp, 2rp+1)

  for (int t = 1; t < 512; ++t) {
    const int tm1 = t - 1;
    const int par = (t - 1) & 1;
    // --- x A-frags (plain cached loads; before the poll => overlap) ---
    size_t xoff = (size_t)t * 8192 + (g * 16 + lr) * 64 + lq * 16;
    int4v axh = *reinterpret_cast<const int4v*>(xqh + xoff);
    int4v axl = *reinterpret_cast<const int4v*>(xql + xoff);

    // --- partial wait: this wave's 8 producer blocks x 4 flags = 32 ---
    {
      const int* fp = flags + g * 128 + wv * 32 + (ln & 31);
      int guard = 0;
      for (;;) {
        int v;
        asm volatile("global_load_dword %0, %1, off sc0 sc1\n\ts_waitcnt vmcnt(0)"
                     : "=v"(v) : "v"(fp) : "memory");
        if (__all(v >= tm1)) break;
        if (++guard > (1 << 18)) break;   // hang-safety valve
      }
    }

    // --- h A-frags: packed shorts, 2 dwordx4 per tau (coherence point) ---
    int4v hw[4][2];
#pragma unroll
    for (int j = 0; j < 4; ++j) {
      int voff = par * 262144 + hoffA[j];
      asm volatile("global_load_dwordx4 %0, %1, %2 sc0 sc1"
                   : "=v"(hw[j][0]) : "v"(voff), "s"(Hp));
      asm volatile("global_load_dwordx4 %0, %1, %2 offset:16 sc0 sc1"
                   : "=v"(hw[j][1]) : "v"(voff), "s"(Hp));
    }
    asm volatile("s_waitcnt vmcnt(0)" ::: "memory");
    __builtin_amdgcn_sched_barrier(0);

    // --- split channels (v_perm) + MFMA (weights from LDS / pinned regs) ---
    int4v hh[8], hl[8];
#pragma unroll
    for (int nt = 0; nt < 8; ++nt) {
      hh[nt] = (int4v){0, 0, 0, 0};
      hl[nt] = (int4v){0, 0, 0, 0};
    }
#pragma unroll
    for (int j = 0; j < 4; ++j) {
      unsigned int w0 = (unsigned int)hw[j][0].x, w1 = (unsigned int)hw[j][0].y;
      unsigned int w2 = (unsigned int)hw[j][0].z, w3 = (unsigned int)hw[j][0].w;
      unsigned int w4 = (unsigned int)hw[j][1].x, w5 = (unsigned int)hw[j][1].y;
      unsigned int w6 = (unsigned int)hw[j][1].z, w7 = (unsigned int)hw[j][1].w;
      int4v ah, al;
      ah[0] = (int)__builtin_amdgcn_perm(w1, w0, 0x07050301u);
      ah[1] = (int)__builtin_amdgcn_perm(w3, w2, 0x07050301u);
      ah[2] = (int)__builtin_amdgcn_perm(w5, w4, 0x07050301u);
      ah[3] = (int)__builtin_amdgcn_perm(w7, w6, 0x07050301u);
      al[0] = (int)__builtin_amdgcn_perm(w1, w0, 0x06040200u);
      al[1] = (int)__builtin_amdgcn_perm(w3, w2, 0x06040200u);
      al[2] = (int)__builtin_amdgcn_perm(w5, w4, 0x06040200u);
      al[3] = (int)__builtin_amdgcn_perm(w7, w6, 0x06040200u);
      if (wv == 3 && j >= 2) {
#pragma unroll
        for (int nt = 0; nt < 8; ++nt) {
          hh[nt] = MFMA_I8(ah, bs[j - 2][nt], hh[nt]);
          hl[nt] = MFMA_I8(al, bs[j - 2][nt], hl[nt]);
        }
      } else {
        const char* wp = wlds + ((wv * 4 + j) << 10) + ln * 16;
#pragma unroll
        for (int nt = 0; nt < 8; ++nt) {
          const int4v bf = *reinterpret_cast<const int4v*>(wp + nt * 14336);
          hh[nt] = MFMA_I8(ah, bf, hh[nt]);
          hl[nt] = MFMA_I8(al, bf, hl[nt]);
        }
      }
    }
    // x contributions fold into this wave's 2 ntiles
    int4v xa0 = (int4v){0, 0, 0, 0}, xb0 = (int4v){0, 0, 0, 0};
    int4v xa1 = (int4v){0, 0, 0, 0}, xb1 = (int4v){0, 0, 0, 0};
    xa0 = MFMA_I8(axh, bqx[0], xa0);
    xb0 = MFMA_I8(axl, bqx[0], xb0);
    xa1 = MFMA_I8(axh, bqx[1], xa1);
    xb1 = MFMA_I8(axl, bqx[1], xb1);

    // --- combine to f32, write pbuf ---
#pragma unroll
    for (int nt = 0; nt < 8; ++nt) {
      float4v o;
#pragma unroll
      for (int i = 0; i < 4; ++i) {
        float f = (float)hh[nt][i] * C_HI + (float)hl[nt][i] * C_HLO;
        if (nt == wv * 2)
          f += sx * ((float)xa0[i] * C_HI + (float)xb0[i] * C_XLO);
        if (nt == wv * 2 + 1)
          f += sx * ((float)xa1[i] * C_HI + (float)xb1[i] * C_XLO);
        o[i] = scq[nt] * f;
      }
      *reinterpret_cast<float4v*>(&pbuf[wv][nt][lr][lq * 4]) = o;
    }
    __syncthreads();   // bar1: partials visible

    // --- pointwise: reduce 4 wave-partials (rows 2rp,2rp+1, col gcb) ---
    float ga0[4], ga1[4];
#pragma unroll
    for (int q = 0; q < 4; ++q) {
      ga0[q] = pbuf[0][q * 2 + nlo][cc][2 * rp] + pbuf[1][q * 2 + nlo][cc][2 * rp] +
               pbuf[2][q * 2 + nlo][cc][2 * rp] + pbuf[3][q * 2 + nlo][cc][2 * rp];
      ga1[q] = pbuf[0][q * 2 + nlo][cc][2 * rp + 1] + pbuf[1][q * 2 + nlo][cc][2 * rp + 1] +
               pbuf[2][q * 2 + nlo][cc][2 * rp + 1] + pbuf[3][q * 2 + nlo][cc][2 * rp + 1];
    }
    __syncthreads();   // bar2: pbuf reads done before next step's writes

    float lb0 = bias2[0], lb1 = bias2[1], lb2 = bias2[2], lb3 = bias2[3];
    if (t == 1) {
      lb0 = b1[gcb];
      lb1 = b1[1024 + gcb];
      lb2 = b1[2048 + gcb];
      lb3 = b1[3072 + gcb];
    }
    float i0 = sigm(ga0[0] + lb0), f0 = sigm(ga0[1] + lb1);
    float G0 = tanh_f(ga0[2] + lb2), o0 = sigm(ga0[3] + lb3);
    float i1 = sigm(ga1[0] + lb0), f1 = sigm(ga1[1] + lb1);
    float G1 = tanh_f(ga1[2] + lb2), o1 = sigm(ga1[3] + lb3);
    cs0 = f0 * cs0 + i0 * G0;
    cs1 = f1 * cs1 + i1 * G1;
    float hv0 = o0 * tanh_f(cs0);
    float hv1 = o1 * tanh_f(cs1);

    // --- quantize h -> packed short (hi<<8|lo), publish, drain, flag ---
    float s0 = hv0 * 127.0f, q0 = rintf(s0), r0f = rintf((s0 - q0) * 254.0f);
    float s1 = hv1 * 127.0f, q1 = rintf(s1), r1f = rintf((s1 - q1) * 254.0f);
    int u0 = ((((int)q0) & 0xff) << 8) | (((int)r0f) & 0xff);
    int u1 = ((((int)q1) & 0xff) << 8) | (((int)r1f) & 0xff);
    const int r0 = g * 16 + rp * 2;
    char* st0 = Hp + (t & 1) * 262144 + r0 * 2048 + gcb * 2;
    asm volatile("global_store_short %0, %1, off sc0 sc1" :: "v"(st0), "v"(u0) : "memory");
    asm volatile("global_store_short %0, %1, off sc0 sc1" :: "v"(st0 + 2048), "v"(u1) : "memory");
    asm volatile("s_waitcnt vmcnt(0)" ::: "memory");
    if (ln == 0) {
      int* fp2 = flags + g * 128 + mb * 4 + wv;
      asm volatile("global_store_dword %0, %1, off sc0 sc1" :: "v"(fp2), "v"(t) : "memory");
    }

    // --- W_lin partial for this block's 32 cols (off-chain) ---
    float pa = hv0 * wl, pb = hv1 * wl;
    pa += __shfl_xor(pa, 1); pb += __shfl_xor(pb, 1);
    pa += __shfl_xor(pa, 2); pb += __shfl_xor(pb, 2);
    pa += __shfl_xor(pa, 4); pb += __shfl_xor(pb, 4);
    pa += __shfl_xor(pa, 8); pb += __shfl_xor(pb, 8);
    pa += __shfl_xor(pa, 16); pb += __shfl_xor(pb, 16);
    if (c == 0) {
      outp[(size_t)(t * 128 + r0) * 32 + mb] = pa;
      outp[(size_t)(t * 128 + r0 + 1) * 32 + mb] = pb;
    }
  }
}

// ---- out[t][b] = b_lin + sum_mb outp[t][b][mb]; rows t=0 -> INIT_OUT ----
__global__ void finalize(const float* __restrict__ outp, const float* __restrict__ b_lin,
                         float* __restrict__ out) {
  int tid = threadIdx.x;
  int ln = tid & 63;
  int wv = tid >> 6;
  int half = ln >> 5;
  int lane = ln & 31;
  int row = blockIdx.x * 8 + wv * 2 + half;   // < 65536
  float v = outp[(size_t)row * 32 + lane];
  v += __shfl_xor(v, 1);
  v += __shfl_xor(v, 2);
  v += __shfl_xor(v, 4);
  v += __shfl_xor(v, 8);
  v += __shfl_xor(v, 16);
  if (lane == 0) out[row] = (row < 128) ? 1e-9f : (v + b_lin[0]);
}

extern "C" void kernel_launch(void* const* d_in, const int* in_sizes, int n_in,
                              void* d_out, int out_size, void* d_ws, size_t ws_size,
                              hipStream_t stream) {
  const float* x = (const float*)d_in[0];
  const float* W_ih = (const float*)d_in[1];
  const float* W_hh = (const float*)d_in[2];
  const float* b_ih = (const float*)d_in[3];
  const float* b_hh = (const float*)d_in[4];
  const float* W_lin = (const float*)d_in[5];
  const float* b_lin = (const float*)d_in[6];
  float* out = (float*)d_out;

  char* ws = (char*)d_ws;
  const size_t O_WQ   = 0;           // 4096*1088      = 4456448
  const size_t O_SCOL = 4456448;     // 16384
  const size_t O_B1   = 4472832;     // 16384
  const size_t O_B2   = 4489216;     // 16384
  const size_t O_SX   = 4505600;     // 64
  const size_t O_XH   = 4505664;     // 512*128*64     = 4194304
  const size_t O_XL   = 8699968;     // 4194304
  const size_t O_HP   = 12894272;    // 2*128*1024*2   = 524288
  const size_t O_FLAG = 13418560;    // 4096
  const size_t O_OUTP = 13422656;    // 512*128*32*4   = 8388608
  const size_t O_END  = 21811264;
  if (ws_size < O_END) return;       // insufficient scratch -> fail loudly

  signed char* Wq = (signed char*)(ws + O_WQ);
  float* scol = (float*)(ws + O_SCOL);
  float* b1 = (float*)(ws + O_B1);
  float* b2 = (float*)(ws + O_B2);
  unsigned int* sxu = (unsigned int*)(ws + O_SX);
  signed char* xqh = (signed char*)(ws + O_XH);
  signed char* xql = (signed char*)(ws + O_XL);
  char* Hp = ws + O_HP;
  int* flags = (int*)(ws + O_FLAG);
  float* outp = (float*)(ws + O_OUTP);

  initz<<<512, 256, 0, stream>>>((unsigned int*)Hp, flags, sxu);
  prep_ax<<<1024, 256, 0, stream>>>(x, sxu);
  prep_wq<<<4096, 256, 0, stream>>>(W_ih, W_hh, W_lin, b_ih, b_hh, b_lin, Wq, scol, b1, b2);
  prep_x2<<<16384, 256, 0, stream>>>(x, sxu, xqh, xql);
  lstm_rec<<<256, 256, 0, stream>>>(Wq, scol, xqh, xql, sxu, b1, b2, W_lin, Hp, outp, flags);
  finalize<<<8192, 256, 0, stream>>>(outp, b_lin, out);
}